// Round 17
// baseline (72.549 us; speedup 1.0000x reference)
//
#include <hip/hip_runtime.h>
#include <math.h>

#define NN 8000
#define NE 80000
#define NP 6
#define NR 6
#define NA 20
#define NC 9
#define PAC (NP*NA*NC)   // 1080
#define TW  360          // T row: [p][a][i], 6*20*3
#define EDW 24           // per-slot packed row: 48 bf16 = 24 uints (96 B)
#define CUT 5.5f
#define EPSV 1e-9f
#define EB2 32           // edges per LDS stage in node_accum (2 half-windows)

__constant__ int   c_lx[NA]  = {0, 1,0,0, 2,1,1,0,0,0, 3,2,2,1,1,1,0,0,0,0};
__constant__ int   c_ly[NA]  = {0, 0,1,0, 0,1,0,2,1,0, 0,1,0,2,1,0,3,2,1,0};
__constant__ int   c_lz[NA]  = {0, 0,0,1, 0,0,1,0,1,2, 0,0,1,0,1,2,0,1,2,3};
__constant__ int   c_ls[NA]  = {0, 1,1,1, 2,2,2,2,2,2, 3,3,3,3,3,3,3,3,3,3};
__constant__ float c_pref[NA]= {1.f, 1.f,1.f,1.f, 1.f,2.f,2.f,1.f,2.f,1.f,
                                1.f,3.f,3.f,3.f,6.f,3.f,1.f,3.f,3.f,1.f};

__device__ __forceinline__ int spec_of(int z) { return z == 1 ? 0 : (z == 6 ? 1 : 2); }

// pack two f32 -> one uint of 2 bf16 (RNE); element a in low half
__device__ __forceinline__ unsigned pk2(float a, float b) {
    unsigned ua = __float_as_uint(a);
    unsigned ub = __float_as_uint(b);
    ua += 0x7FFFu + ((ua >> 16) & 1u);
    ub += 0x7FFFu + ((ub >> 16) & 1u);
    return (ua >> 16) | (ub & 0xFFFF0000u);
}
__device__ __forceinline__ float blo(unsigned u) { return __uint_as_float(u << 16); }
__device__ __forceinline__ float bhi(unsigned u) { return __uint_as_float(u & 0xFFFF0000u); }
__device__ __forceinline__ float bfh(const unsigned* E, int f) {
    unsigned w = E[f >> 1];
    return (f & 1) ? bhi(w) : blo(w);
}

// ---------- 1a. zero histogram ----------
__global__ __launch_bounds__(256) void zero_cnt(int* __restrict__ cnt)
{
    const int i = blockIdx.x * blockDim.x + threadIdx.x;
    if (i < NN) cnt[i] = 0;
}

// ---------- 1b. grid-parallel histogram ----------
__global__ __launch_bounds__(256) void hist(const int* __restrict__ ei, int* __restrict__ cnt)
{
    const int i = blockIdx.x * blockDim.x + threadIdx.x;
    if (i >= NE/4) return;
    const int4 r4 = ((const int4*)(ei + NE))[i];
    atomicAdd(&cnt[r4.x], 1);
    atomicAdd(&cnt[r4.y], 1);
    atomicAdd(&cnt[r4.z], 1);
    atomicAdd(&cnt[r4.w], 1);
}

// ---------- 1c. exclusive scan (single block, int4 loads, shuffle) ----------
__global__ __launch_bounds__(1024) void csr_scan(const int* __restrict__ cnt,
                                                 int* __restrict__ off, int* __restrict__ cur)
{
    __shared__ int wsum[16];
    const int t = threadIdx.x;
    int v[8]; int sum = 0;
    if (t < 1000) {
        const int4 a = ((const int4*)cnt)[2*t];
        const int4 b = ((const int4*)cnt)[2*t + 1];
        v[0]=a.x; v[1]=a.y; v[2]=a.z; v[3]=a.w;
        v[4]=b.x; v[5]=b.y; v[6]=b.z; v[7]=b.w;
        #pragma unroll
        for (int j = 0; j < 8; ++j) sum += v[j];
    } else {
        #pragma unroll
        for (int j = 0; j < 8; ++j) v[j] = 0;
    }
    const int lane = t & 63, w = t >> 6;   // 16 waves
    int x = sum;
    #pragma unroll
    for (int d = 1; d < 64; d <<= 1) {
        int y = __shfl_up(x, d);
        if (lane >= d) x += y;
    }
    if (lane == 63) wsum[w] = x;
    __syncthreads();
    if (t < 64) {
        int y = (t < 16) ? wsum[t] : 0;
        #pragma unroll
        for (int d = 1; d < 16; d <<= 1) {
            int z = __shfl_up(y, d);
            if (lane >= d) y += z;
        }
        if (t < 16) wsum[t] = y;
    }
    __syncthreads();
    if (t < 1000) {
        int excl = ((w > 0) ? wsum[w - 1] : 0) + (x - sum);
        const int base = t * 8;
        #pragma unroll
        for (int j = 0; j < 8; ++j) {
            off[base + j] = excl;
            cur[base + j] = excl;
            excl += v[j];
        }
    }
    if (t == 0) off[NN] = NE;
}

// ---------- 2. fused CSR-fill + per-edge basis (e-coalesced in, slot-ordered out) ----------
__global__ __launch_bounds__(256) void fill_basis(
    const float* __restrict__ pos, const int* __restrict__ atnum,
    const int* __restrict__ ei, const float* __restrict__ shifts,
    const float* __restrict__ embW, const float* __restrict__ radW,
    int* __restrict__ cur,
    unsigned* __restrict__ edat, int* __restrict__ slist, float* __restrict__ fclist)
{
    const int e = blockIdx.x * blockDim.x + threadIdx.x;
    if (e >= NE) return;
    const int s = ei[e];
    const int r = ei[NE + e];
    const int slot = atomicAdd(&cur[r], 1);

    const float dx = pos[r*3+0] - pos[s*3+0] + shifts[e*3+0];
    const float dy = pos[r*3+1] - pos[s*3+1] + shifts[e*3+1];
    const float dz = pos[r*3+2] - pos[s*3+2] + shifts[e*3+2];
    const float len = sqrtf(dx*dx + dy*dy + dz*dz);
    const float inv = 1.f / (len + EPSV);
    const float ux = dx*inv, uy = dy*inv, uz = dz*inv;

    const float u  = len / CUT;
    const float u2 = u*u;
    const float u6 = u2*u2*u2;
    const float fcut = (u < 1.f) ? (1.f - 28.f*u6 + 48.f*u6*u - 21.f*u6*u2) : 0.f;

    float E[48];

    float rad[NR];
    {
        const float th = len * (float)(M_PI / (double)CUT);
        float sc, cc;
        sincosf(th, &sc, &cc);
        const float cr = sqrtf(2.f/CUT) * inv;
        const float c2 = 2.f * cc;
        float skm1 = 0.f, sk = sc;
        #pragma unroll
        for (int k = 0; k < NR; ++k) {
            rad[k] = cr * sk;
            const float nx = c2 * sk - skm1;
            skm1 = sk; sk = nx;
        }
    }

    #pragma unroll
    for (int l = 0; l < 4; ++l)
        #pragma unroll
        for (int p = 0; p < NP; ++p) {
            float acc = 0.f;
            #pragma unroll
            for (int rr = 0; rr < NR; ++rr) acc += rad[rr] * radW[l*NR*NP + rr*NP + p];
            E[l*NP + p] = fcut * acc;
        }

    {
        float px[4] = {1.f, ux, ux*ux, ux*ux*ux};
        float py[4] = {1.f, uy, uy*uy, uy*uy*uy};
        float pz[4] = {1.f, uz, uz*uz, uz*uz*uz};
        #pragma unroll
        for (int a = 0; a < NA; ++a)
            E[24 + a] = px[c_lx[a]] * py[c_ly[a]] * pz[c_lz[a]];
    }
    const int ss = spec_of(atnum[s]);
    E[44] = embW[ss*3+0]; E[45] = embW[ss*3+1]; E[46] = embW[ss*3+2];
    E[47] = 0.f;

    unsigned P[EDW];
    #pragma unroll
    for (int f = 0; f < EDW; ++f) P[f] = pk2(E[2*f], E[2*f+1]);

    slist[slot]  = s | (ss << 16);
    fclist[slot] = fcut;
    uint4* __restrict__ E4 = (uint4*)(edat + (size_t)slot * EDW);
    #pragma unroll
    for (int f = 0; f < 6; ++f)
        E4[f] = make_uint4(P[4*f], P[4*f+1], P[4*f+2], P[4*f+3]);
}

// ---------- 3. node-centric T accumulation: 256 thr, 2 half-windows in parallel ----------
__global__ __launch_bounds__(256) void node_accum(
    const unsigned* __restrict__ edat, const int* __restrict__ off,
    unsigned short* __restrict__ Th)
{
    const int n = blockIdx.x;
    const int tid = threadIdx.x;
    const int half = tid >> 7;            // 0: edges [0,16) of window, 1: [16,32)
    const int ht = tid & 127;
    const bool act = (ht < NP * NA);      // 120 lanes per half
    const int p = ht / NA, a = ht % NA;
    const int l = (a >= 1) + (a >= 4) + (a >= 10);
    const int iR = l*NP + p;

    float acc0 = 0.f, acc1 = 0.f, acc2 = 0.f;

    __shared__ uint4 sE4[EB2 * 6];        // 32 edges * 96 B = 3 KB
    const unsigned* sE = (const unsigned*)sE4;
    __shared__ __align__(16) float sRow[2][TW];

    const int st = off[n], en = off[n+1];
    const uint4* __restrict__ gbase = (const uint4*)edat;
    for (int i0 = st; i0 < en; i0 += EB2) {
        const int nb = min(EB2, en - i0);    // block-uniform
        __syncthreads();
        for (int q = tid; q < nb * 6; q += 256)
            sE4[q] = gbase[(size_t)i0 * 6 + q];
        __syncthreads();
        if (act) {
            const int b0 = half ? min(16, nb) : 0;
            const int b1 = half ? nb : min(16, nb);
            for (int b = b0; b < b1; ++b) {
                const unsigned* E = &sE[b * EDW];
                const float ra = bfh(E, iR) * bfh(E, 24 + a);
                acc0 = fmaf(ra, bfh(E, 44), acc0);
                acc1 = fmaf(ra, bfh(E, 45), acc1);
                acc2 = fmaf(ra, bfh(E, 46), acc2);
            }
        }
    }
    if (act) {
        sRow[half][ht*3 + 0] = acc0;
        sRow[half][ht*3 + 1] = acc1;
        sRow[half][ht*3 + 2] = acc2;
    }
    __syncthreads();

    // combine halves + pack 360 floats -> 45 uint4 (8 bf16 each)
    if (tid < 45) {
        float s8[8];
        #pragma unroll
        for (int j = 0; j < 8; ++j)
            s8[j] = sRow[0][8*tid + j] + sRow[1][8*tid + j];
        ((uint4*)(Th + (size_t)n * TW))[tid] =
            make_uint4(pk2(s8[0], s8[1]), pk2(s8[2], s8[3]),
                       pk2(s8[4], s8[5]), pk2(s8[6], s8[7]));
    }
}

// ---------- 4. fused MP gather: 256 thr, halves gather alternating slots, 4-wide ----------
__global__ __launch_bounds__(256) void node_mp_final(
    const unsigned short* __restrict__ Th,
    const int* __restrict__ atnum,
    const int* __restrict__ slist, const float* __restrict__ fclist,
    const int* __restrict__ off, const float* __restrict__ embW,
    const float* __restrict__ memc, float* __restrict__ out)
{
    const int n = blockIdx.x;
    const int tid = threadIdx.x;
    const int half = tid >> 7;
    const int ht = tid & 127;

    __shared__ int   sS[128];
    __shared__ float sF[128];
    __shared__ __align__(16) float sT[TW];
    __shared__ __align__(16) float sB[2][3][TW];  // per-half partial buckets
    __shared__ __align__(16) float sA[2 * PAC];   // A0_n | A1_n
    __shared__ __align__(16) float sOut[544];

    const int st = off[n], en = off[n+1];
    const bool gact = (ht < 90);                  // uint2 chunks of T row
    float4 bA = {0,0,0,0}, bB = {0,0,0,0}, bC = {0,0,0,0};

    for (int w0 = st; w0 < en; w0 += 128) {
        const int nb = min(128, en - w0);         // block-uniform
        __syncthreads();
        if (tid < nb) { sS[tid] = slist[w0 + tid]; sF[tid] = fclist[w0 + tid]; }
        __syncthreads();
        if (gact) {
            #define ACCV(vv, ff, kk) { \
                const float e0 = blo(vv.x), e1 = bhi(vv.x), e2 = blo(vv.y), e3 = bhi(vv.y); \
                if (kk == 0) { \
                    bA.x = fmaf(ff, e0, bA.x); bA.y = fmaf(ff, e1, bA.y); \
                    bA.z = fmaf(ff, e2, bA.z); bA.w = fmaf(ff, e3, bA.w); \
                } else if (kk == 1) { \
                    bB.x = fmaf(ff, e0, bB.x); bB.y = fmaf(ff, e1, bB.y); \
                    bB.z = fmaf(ff, e2, bB.z); bB.w = fmaf(ff, e3, bB.w); \
                } else { \
                    bC.x = fmaf(ff, e0, bC.x); bC.y = fmaf(ff, e1, bC.y); \
                    bC.z = fmaf(ff, e2, bC.z); bC.w = fmaf(ff, e3, bC.w); \
                } }
            // half h covers slots j ≡ h (mod 2); 4-wide unroll per half
            int j = half;
            for (; j + 6 < nb; j += 8) {
                const int   p0 = sS[j+0], p1 = sS[j+2], p2 = sS[j+4], p3 = sS[j+6];
                const float f0 = sF[j+0], f1 = sF[j+2], f2 = sF[j+4], f3 = sF[j+6];
                const uint2 v0 = ((const uint2*)(Th + (size_t)(p0 & 0xFFFF) * TW))[ht];
                const uint2 v1 = ((const uint2*)(Th + (size_t)(p1 & 0xFFFF) * TW))[ht];
                const uint2 v2 = ((const uint2*)(Th + (size_t)(p2 & 0xFFFF) * TW))[ht];
                const uint2 v3 = ((const uint2*)(Th + (size_t)(p3 & 0xFFFF) * TW))[ht];
                ACCV(v0, f0, (p0 >> 16)); ACCV(v1, f1, (p1 >> 16));
                ACCV(v2, f2, (p2 >> 16)); ACCV(v3, f3, (p3 >> 16));
            }
            for (; j < nb; j += 2) {
                const int pj = sS[j];
                const float fj = sF[j];
                const uint2 v = ((const uint2*)(Th + (size_t)(pj & 0xFFFF) * TW))[ht];
                ACCV(v, fj, (pj >> 16));
            }
            #undef ACCV
        }
    }

    if (gact) {
        const int q = 4 * ht;
        ((float4*)&sB[half][0][q])[0] = bA;
        ((float4*)&sB[half][1][q])[0] = bB;
        ((float4*)&sB[half][2][q])[0] = bC;
        if (half == 0) {
            uint2 tv = ((const uint2*)(Th + (size_t)n * TW))[ht];
            sT[q+0] = blo(tv.x); sT[q+1] = bhi(tv.x);
            sT[q+2] = blo(tv.y); sT[q+3] = bhi(tv.y);
        }
    }
    __syncthreads();

    const float mc  = memc[0];
    const float mpn = 0.3162277660168379f;  // 1/sqrt(10)
    if (tid < NP * NA) {                    // 120 threads: pa
        const int sr = spec_of(atnum[n]);
        const float enj[3] = {embW[sr*3+0], embW[sr*3+1], embW[sr*3+2]};
        const int q = tid * 3;
        #pragma unroll
        for (int i = 0; i < 3; ++i) {
            const float ti = sT[q + i];
            const float b0 = sB[0][0][q + i] + sB[1][0][q + i];
            const float b1 = sB[0][1][q + i] + sB[1][1][q + i];
            const float b2 = sB[0][2][q + i] + sB[1][2][q + i];
            #pragma unroll
            for (int j = 0; j < 3; ++j) {
                const float a0v = ti * enj[j];
                const float agg = embW[0*3+j]*b0 + embW[1*3+j]*b1 + embW[2*3+j]*b2;
                sA[tid*NC + i*3 + j]        = a0v;
                sA[PAC + tid*NC + i*3 + j]  = fmaf(mc, a0v, mpn * agg);
            }
        }
    }
    __syncthreads();

    if (tid < NP * NC) {
        const int p = tid / NC, c = tid % NC;
        const int base = p * (NA * NC) + c;
        float s20[4] = {0.f,0.f,0.f,0.f};
        float s21[4] = {0.f,0.f,0.f,0.f};
        #pragma unroll
        for (int a = 0; a < NA; ++a) {
            const int ll = c_ls[a];
            const float pr = c_pref[a];
            const float x0 = sA[base + a*NC];
            const float x1 = sA[PAC + base + a*NC];
            s20[ll] = fmaf(pr * x0, x0, s20[ll]);
            s21[ll] = fmaf(pr * x1, x1, s21[ll]);
        }
        const int ob = p*90 + c*2;
        sOut[ob]     = sA[base];
        sOut[ob + 1] = sA[PAC + base];
        #pragma unroll
        for (int ll = 0; ll < 4; ++ll) {
            sOut[ob + (ll+1)*18]     = s20[ll];
            sOut[ob + (ll+1)*18 + 1] = s21[ll];
        }
    }
    __syncthreads();

    float4* __restrict__ o4 = (float4*)(out + (size_t)n * 540);
    if (tid < 135) o4[tid] = ((const float4*)sOut)[tid];
}

extern "C" void kernel_launch(void* const* d_in, const int* in_sizes, int n_in,
                              void* d_out, int out_size, void* d_ws, size_t ws_size,
                              hipStream_t stream) {
    const float* pos    = (const float*)d_in[0];
    const int*   atnum  = (const int*)d_in[1];
    const int*   ei     = (const int*)d_in[2];
    const float* shifts = (const float*)d_in[3];
    const float* embW   = (const float*)d_in[4];
    const float* radW   = (const float*)d_in[5];
    const float* memc   = (const float*)d_in[6];
    float* out = (float*)d_out;

    unsigned*       edat = (unsigned*)d_ws;                    // NE*24 uints (7.68 MB)
    unsigned short* Th   = (unsigned short*)(edat + (size_t)NE * EDW);  // NN*360 bf16 (5.76 MB)
    float* fclist = (float*)(Th + (size_t)NN * TW);            // NE
    int*   cnt    = (int*)(fclist + NE);                       // NN
    int*   off    = cnt + NN;                                  // NN+1
    int*   cur    = off + NN + 1;                              // NN
    int*   slist  = cur + NN;                                  // NE

    zero_cnt<<<(NN+255)/256, 256, 0, stream>>>(cnt);
    hist<<<(NE/4+255)/256, 256, 0, stream>>>(ei, cnt);
    csr_scan<<<1, 1024, 0, stream>>>(cnt, off, cur);
    fill_basis<<<(NE+255)/256, 256, 0, stream>>>(pos, atnum, ei, shifts, embW, radW,
                                                 cur, edat, slist, fclist);
    node_accum<<<NN, 256, 0, stream>>>(edat, off, Th);
    node_mp_final<<<NN, 256, 0, stream>>>(Th, atnum, slist, fclist, off, embW, memc, out);
}

// Round 18
// 68.392 us; speedup vs baseline: 1.0608x; 1.0608x over previous
//
#include <hip/hip_runtime.h>
#include <math.h>

#define NN 8000
#define NE 80000
#define NP 6
#define NR 6
#define NA 20
#define NC 9
#define PAC (NP*NA*NC)   // 1080
#define TW  360          // T row: [p][a][i], 6*20*3
#define EDW 24           // per-slot packed row: 48 bf16 = 24 uints (96 B)
#define CUT 5.5f
#define EPSV 1e-9f
#define EB 16            // edges per LDS stage in node_accum

__constant__ int   c_lx[NA]  = {0, 1,0,0, 2,1,1,0,0,0, 3,2,2,1,1,1,0,0,0,0};
__constant__ int   c_ly[NA]  = {0, 0,1,0, 0,1,0,2,1,0, 0,1,0,2,1,0,3,2,1,0};
__constant__ int   c_lz[NA]  = {0, 0,0,1, 0,0,1,0,1,2, 0,0,1,0,1,2,0,1,2,3};
__constant__ int   c_ls[NA]  = {0, 1,1,1, 2,2,2,2,2,2, 3,3,3,3,3,3,3,3,3,3};
__constant__ float c_pref[NA]= {1.f, 1.f,1.f,1.f, 1.f,2.f,2.f,1.f,2.f,1.f,
                                1.f,3.f,3.f,3.f,6.f,3.f,1.f,3.f,3.f,1.f};

__device__ __forceinline__ int spec_of(int z) { return z == 1 ? 0 : (z == 6 ? 1 : 2); }

// pack two f32 -> one uint of 2 bf16 (RNE); element a in low half
__device__ __forceinline__ unsigned pk2(float a, float b) {
    unsigned ua = __float_as_uint(a);
    unsigned ub = __float_as_uint(b);
    ua += 0x7FFFu + ((ua >> 16) & 1u);
    ub += 0x7FFFu + ((ub >> 16) & 1u);
    return (ua >> 16) | (ub & 0xFFFF0000u);
}
__device__ __forceinline__ float blo(unsigned u) { return __uint_as_float(u << 16); }
__device__ __forceinline__ float bhi(unsigned u) { return __uint_as_float(u & 0xFFFF0000u); }
__device__ __forceinline__ float bfh(const unsigned* E, int f) {
    unsigned w = E[f >> 1];
    return (f & 1) ? bhi(w) : blo(w);
}

// ---------- 1a. zero histogram ----------
__global__ __launch_bounds__(256) void zero_cnt(int* __restrict__ cnt)
{
    const int i = blockIdx.x * blockDim.x + threadIdx.x;
    if (i < NN) cnt[i] = 0;
}

// ---------- 1b. grid-parallel histogram ----------
__global__ __launch_bounds__(256) void hist(const int* __restrict__ ei, int* __restrict__ cnt)
{
    const int i = blockIdx.x * blockDim.x + threadIdx.x;
    if (i >= NE/4) return;
    const int4 r4 = ((const int4*)(ei + NE))[i];
    atomicAdd(&cnt[r4.x], 1);
    atomicAdd(&cnt[r4.y], 1);
    atomicAdd(&cnt[r4.z], 1);
    atomicAdd(&cnt[r4.w], 1);
}

// ---------- 1c. exclusive scan (single block, int4 loads, shuffle) ----------
__global__ __launch_bounds__(1024) void csr_scan(const int* __restrict__ cnt,
                                                 int* __restrict__ off, int* __restrict__ cur)
{
    __shared__ int wsum[16];
    const int t = threadIdx.x;
    int v[8]; int sum = 0;
    if (t < 1000) {
        const int4 a = ((const int4*)cnt)[2*t];
        const int4 b = ((const int4*)cnt)[2*t + 1];
        v[0]=a.x; v[1]=a.y; v[2]=a.z; v[3]=a.w;
        v[4]=b.x; v[5]=b.y; v[6]=b.z; v[7]=b.w;
        #pragma unroll
        for (int j = 0; j < 8; ++j) sum += v[j];
    } else {
        #pragma unroll
        for (int j = 0; j < 8; ++j) v[j] = 0;
    }
    const int lane = t & 63, w = t >> 6;   // 16 waves
    int x = sum;
    #pragma unroll
    for (int d = 1; d < 64; d <<= 1) {
        int y = __shfl_up(x, d);
        if (lane >= d) x += y;
    }
    if (lane == 63) wsum[w] = x;
    __syncthreads();
    if (t < 64) {
        int y = (t < 16) ? wsum[t] : 0;
        #pragma unroll
        for (int d = 1; d < 16; d <<= 1) {
            int z = __shfl_up(y, d);
            if (lane >= d) y += z;
        }
        if (t < 16) wsum[t] = y;
    }
    __syncthreads();
    if (t < 1000) {
        int excl = ((w > 0) ? wsum[w - 1] : 0) + (x - sum);
        const int base = t * 8;
        #pragma unroll
        for (int j = 0; j < 8; ++j) {
            off[base + j] = excl;
            cur[base + j] = excl;
            excl += v[j];
        }
    }
    if (t == 0) off[NN] = NE;
}

// ---------- 2. fused CSR-fill + per-edge basis (e-coalesced in, slot-ordered out) ----------
__global__ __launch_bounds__(256) void fill_basis(
    const float* __restrict__ pos, const int* __restrict__ atnum,
    const int* __restrict__ ei, const float* __restrict__ shifts,
    const float* __restrict__ embW, const float* __restrict__ radW,
    int* __restrict__ cur,
    unsigned* __restrict__ edat, int* __restrict__ slist, float* __restrict__ fclist)
{
    const int e = blockIdx.x * blockDim.x + threadIdx.x;
    if (e >= NE) return;
    const int s = ei[e];
    const int r = ei[NE + e];
    const int slot = atomicAdd(&cur[r], 1);

    const float dx = pos[r*3+0] - pos[s*3+0] + shifts[e*3+0];
    const float dy = pos[r*3+1] - pos[s*3+1] + shifts[e*3+1];
    const float dz = pos[r*3+2] - pos[s*3+2] + shifts[e*3+2];
    const float len = sqrtf(dx*dx + dy*dy + dz*dz);
    const float inv = 1.f / (len + EPSV);
    const float ux = dx*inv, uy = dy*inv, uz = dz*inv;

    const float u  = len / CUT;
    const float u2 = u*u;
    const float u6 = u2*u2*u2;
    const float fcut = (u < 1.f) ? (1.f - 28.f*u6 + 48.f*u6*u - 21.f*u6*u2) : 0.f;

    float E[48];

    float rad[NR];
    {
        const float th = len * (float)(M_PI / (double)CUT);
        float sc, cc;
        sincosf(th, &sc, &cc);
        const float cr = sqrtf(2.f/CUT) * inv;
        const float c2 = 2.f * cc;
        float skm1 = 0.f, sk = sc;
        #pragma unroll
        for (int k = 0; k < NR; ++k) {
            rad[k] = cr * sk;
            const float nx = c2 * sk - skm1;
            skm1 = sk; sk = nx;
        }
    }

    #pragma unroll
    for (int l = 0; l < 4; ++l)
        #pragma unroll
        for (int p = 0; p < NP; ++p) {
            float acc = 0.f;
            #pragma unroll
            for (int rr = 0; rr < NR; ++rr) acc += rad[rr] * radW[l*NR*NP + rr*NP + p];
            E[l*NP + p] = fcut * acc;
        }

    {
        float px[4] = {1.f, ux, ux*ux, ux*ux*ux};
        float py[4] = {1.f, uy, uy*uy, uy*uy*uy};
        float pz[4] = {1.f, uz, uz*uz, uz*uz*uz};
        #pragma unroll
        for (int a = 0; a < NA; ++a)
            E[24 + a] = px[c_lx[a]] * py[c_ly[a]] * pz[c_lz[a]];
    }
    const int ss = spec_of(atnum[s]);
    E[44] = embW[ss*3+0]; E[45] = embW[ss*3+1]; E[46] = embW[ss*3+2];
    E[47] = 0.f;

    unsigned P[EDW];
    #pragma unroll
    for (int f = 0; f < EDW; ++f) P[f] = pk2(E[2*f], E[2*f+1]);

    slist[slot]  = s | (ss << 16);
    fclist[slot] = fcut;
    uint4* __restrict__ E4 = (uint4*)(edat + (size_t)slot * EDW);
    #pragma unroll
    for (int f = 0; f < 6; ++f)
        E4[f] = make_uint4(P[4*f], P[4*f+1], P[4*f+2], P[4*f+3]);
}

// ---------- 3. node-centric T accumulation: contiguous slot stream -> bf16 T row ----------
__global__ __launch_bounds__(128) void node_accum(
    const unsigned* __restrict__ edat, const int* __restrict__ off,
    unsigned short* __restrict__ Th)
{
    const int n = blockIdx.x;
    const int tid = threadIdx.x;
    const bool act = (tid < NP * NA);     // 120 threads: tid = p*NA + a
    const int p = tid / NA, a = tid % NA;
    const int l = (a >= 1) + (a >= 4) + (a >= 10);
    const int iR = l*NP + p;

    float acc0 = 0.f, acc1 = 0.f, acc2 = 0.f;

    __shared__ uint4 sE4[EB * 6];
    const unsigned* sE = (const unsigned*)sE4;
    __shared__ __align__(16) float sRow[TW];

    const int st = off[n], en = off[n+1];
    const uint4* __restrict__ gbase = (const uint4*)edat;
    for (int i0 = st; i0 < en; i0 += EB) {
        const int nb = min(EB, en - i0);
        __syncthreads();
        for (int q = tid; q < nb * 6; q += 128)
            sE4[q] = gbase[(size_t)i0 * 6 + q];
        __syncthreads();
        if (act) {
            for (int b = 0; b < nb; ++b) {
                const unsigned* E = &sE[b * EDW];
                const float ra = bfh(E, iR) * bfh(E, 24 + a);
                acc0 = fmaf(ra, bfh(E, 44), acc0);
                acc1 = fmaf(ra, bfh(E, 45), acc1);
                acc2 = fmaf(ra, bfh(E, 46), acc2);
            }
        }
    }
    if (act) {
        sRow[tid*3 + 0] = acc0;
        sRow[tid*3 + 1] = acc1;
        sRow[tid*3 + 2] = acc2;
    }
    __syncthreads();

    // pack 360 floats -> 45 uint4 (8 bf16 each)
    uint4* __restrict__ row = (uint4*)(Th + (size_t)n * TW);
    if (tid < 45) {
        const float* s8 = &sRow[8 * tid];
        row[tid] = make_uint4(pk2(s8[0], s8[1]), pk2(s8[2], s8[3]),
                              pk2(s8[4], s8[5]), pk2(s8[6], s8[7]));
    }
}

// ---------- 4. fused MP gather (bf16 T, species-bucketed, 4-wide) + reconstruct + symmetrize ----------
__global__ __launch_bounds__(128) void node_mp_final(
    const unsigned short* __restrict__ Th,
    const int* __restrict__ atnum,
    const int* __restrict__ slist, const float* __restrict__ fclist,
    const int* __restrict__ off, const float* __restrict__ embW,
    const float* __restrict__ memc, float* __restrict__ out)
{
    const int n = blockIdx.x;
    const int tid = threadIdx.x;

    __shared__ int   sS[128];
    __shared__ float sF[128];
    __shared__ __align__(16) float sT[TW];
    __shared__ __align__(16) float sB[3][TW];
    __shared__ __align__(16) float sA[2 * PAC];   // A0_n | A1_n
    __shared__ __align__(16) float sOut[544];

    const int st = off[n], en = off[n+1];
    const bool gact = (tid < 90);                 // uint2 chunks of T row (90 * 4 bf16)
    float4 bA = {0,0,0,0}, bB = {0,0,0,0}, bC = {0,0,0,0};

    for (int b0 = st; b0 < en; b0 += 128) {
        const int nb = min(128, en - b0);
        __syncthreads();
        if (tid < nb) { sS[tid] = slist[b0 + tid]; sF[tid] = fclist[b0 + tid]; }
        __syncthreads();
        if (gact) {
            #define ACCV(vv, ff, kk) { \
                const float e0 = blo(vv.x), e1 = bhi(vv.x), e2 = blo(vv.y), e3 = bhi(vv.y); \
                if (kk == 0) { \
                    bA.x = fmaf(ff, e0, bA.x); bA.y = fmaf(ff, e1, bA.y); \
                    bA.z = fmaf(ff, e2, bA.z); bA.w = fmaf(ff, e3, bA.w); \
                } else if (kk == 1) { \
                    bB.x = fmaf(ff, e0, bB.x); bB.y = fmaf(ff, e1, bB.y); \
                    bB.z = fmaf(ff, e2, bB.z); bB.w = fmaf(ff, e3, bB.w); \
                } else { \
                    bC.x = fmaf(ff, e0, bC.x); bC.y = fmaf(ff, e1, bC.y); \
                    bC.z = fmaf(ff, e2, bC.z); bC.w = fmaf(ff, e3, bC.w); \
                } }
            int j = 0;
            for (; j + 4 <= nb; j += 4) {
                const int   p0 = sS[j+0], p1 = sS[j+1], p2 = sS[j+2], p3 = sS[j+3];
                const float f0 = sF[j+0], f1 = sF[j+1], f2 = sF[j+2], f3 = sF[j+3];
                const uint2 v0 = ((const uint2*)(Th + (size_t)(p0 & 0xFFFF) * TW))[tid];
                const uint2 v1 = ((const uint2*)(Th + (size_t)(p1 & 0xFFFF) * TW))[tid];
                const uint2 v2 = ((const uint2*)(Th + (size_t)(p2 & 0xFFFF) * TW))[tid];
                const uint2 v3 = ((const uint2*)(Th + (size_t)(p3 & 0xFFFF) * TW))[tid];
                ACCV(v0, f0, (p0 >> 16)); ACCV(v1, f1, (p1 >> 16));
                ACCV(v2, f2, (p2 >> 16)); ACCV(v3, f3, (p3 >> 16));
            }
            for (; j < nb; ++j) {
                const int pj = sS[j];
                const float fj = sF[j];
                const uint2 v = ((const uint2*)(Th + (size_t)(pj & 0xFFFF) * TW))[tid];
                ACCV(v, fj, (pj >> 16));
            }
            #undef ACCV
        }
    }

    if (gact) {
        uint2 tv = ((const uint2*)(Th + (size_t)n * TW))[tid];
        const int q = 4 * tid;
        sT[q+0] = blo(tv.x); sT[q+1] = bhi(tv.x);
        sT[q+2] = blo(tv.y); sT[q+3] = bhi(tv.y);
        ((float4*)&sB[0][q])[0] = bA;
        ((float4*)&sB[1][q])[0] = bB;
        ((float4*)&sB[2][q])[0] = bC;
    }
    __syncthreads();

    const float mc  = memc[0];
    const float mpn = 0.3162277660168379f;  // 1/sqrt(10)
    if (tid < NP * NA) {                    // 120 threads: pa
        const int sr = spec_of(atnum[n]);
        const float enj[3] = {embW[sr*3+0], embW[sr*3+1], embW[sr*3+2]};
        const int q = tid * 3;
        #pragma unroll
        for (int i = 0; i < 3; ++i) {
            const float ti = sT[q + i];
            const float b0 = sB[0][q + i], b1 = sB[1][q + i], b2 = sB[2][q + i];
            #pragma unroll
            for (int j = 0; j < 3; ++j) {
                const float a0v = ti * enj[j];
                const float agg = embW[0*3+j]*b0 + embW[1*3+j]*b1 + embW[2*3+j]*b2;
                sA[tid*NC + i*3 + j]        = a0v;
                sA[PAC + tid*NC + i*3 + j]  = fmaf(mc, a0v, mpn * agg);
            }
        }
    }
    __syncthreads();

    if (tid < NP * NC) {
        const int p = tid / NC, c = tid % NC;
        const int base = p * (NA * NC) + c;
        float s20[4] = {0.f,0.f,0.f,0.f};
        float s21[4] = {0.f,0.f,0.f,0.f};
        #pragma unroll
        for (int a = 0; a < NA; ++a) {
            const int ll = c_ls[a];
            const float pr = c_pref[a];
            const float x0 = sA[base + a*NC];
            const float x1 = sA[PAC + base + a*NC];
            s20[ll] = fmaf(pr * x0, x0, s20[ll]);
            s21[ll] = fmaf(pr * x1, x1, s21[ll]);
        }
        const int ob = p*90 + c*2;
        sOut[ob]     = sA[base];
        sOut[ob + 1] = sA[PAC + base];
        #pragma unroll
        for (int ll = 0; ll < 4; ++ll) {
            sOut[ob + (ll+1)*18]     = s20[ll];
            sOut[ob + (ll+1)*18 + 1] = s21[ll];
        }
    }
    __syncthreads();

    float4* __restrict__ o4 = (float4*)(out + (size_t)n * 540);
    for (int q = tid; q < 135; q += 128)
        o4[q] = ((const float4*)sOut)[q];
}

extern "C" void kernel_launch(void* const* d_in, const int* in_sizes, int n_in,
                              void* d_out, int out_size, void* d_ws, size_t ws_size,
                              hipStream_t stream) {
    const float* pos    = (const float*)d_in[0];
    const int*   atnum  = (const int*)d_in[1];
    const int*   ei     = (const int*)d_in[2];
    const float* shifts = (const float*)d_in[3];
    const float* embW   = (const float*)d_in[4];
    const float* radW   = (const float*)d_in[5];
    const float* memc   = (const float*)d_in[6];
    float* out = (float*)d_out;

    unsigned*       edat = (unsigned*)d_ws;                    // NE*24 uints (7.68 MB)
    unsigned short* Th   = (unsigned short*)(edat + (size_t)NE * EDW);  // NN*360 bf16 (5.76 MB)
    float* fclist = (float*)(Th + (size_t)NN * TW);            // NE
    int*   cnt    = (int*)(fclist + NE);                       // NN
    int*   off    = cnt + NN;                                  // NN+1
    int*   cur    = off + NN + 1;                              // NN
    int*   slist  = cur + NN;                                  // NE

    zero_cnt<<<(NN+255)/256, 256, 0, stream>>>(cnt);
    hist<<<(NE/4+255)/256, 256, 0, stream>>>(ei, cnt);
    csr_scan<<<1, 1024, 0, stream>>>(cnt, off, cur);
    fill_basis<<<(NE+255)/256, 256, 0, stream>>>(pos, atnum, ei, shifts, embW, radW,
                                                 cur, edat, slist, fclist);
    node_accum<<<NN, 128, 0, stream>>>(edat, off, Th);
    node_mp_final<<<NN, 128, 0, stream>>>(Th, atnum, slist, fclist, off, embW, memc, out);
}